// Round 3
// baseline (11892.613 us; speedup 1.0000x reference)
//
#include <hip/hip_runtime.h>
#include <math.h>

// ESN recurrence: x_t = tanh(u_t @ w_in^T + w_bias + W @ h_{t-1}), h_0 = 0.
// B=8, T=4096, D_RES=1024, D_IN=64, fp32.
//
// 256 WGs (= 8 batches x 32 row-chunks) x 256 threads; W slab (32x1024) in
// registers per WG. R3 change vs R2: the counter barrier cost 4 serial
// coherence-point round-trips per step (store-ack, counter RMW, poll, h
// reload) -> 2.3 us/step, VALUBusy 17%. Now DATA-AS-FLAG: each h element is
// published as an atomic 64-bit (f32 value, u32 tag=t+1) pair into a 2-slot
// buffer; consumers poll the pairs directly (poll hit == data arrival).
// No counters, no vmcnt drain, no acquire leg. Two slots are ABA-safe:
// a producer reaches step t+2 only after observing all t+1 tags, which
// transitively proves every WG finished reading slot[t&1] (max skew 1 step).
// The same transitivity leaves just ONE __syncthreads per step (restage->
// compute RAW on the double-buffered LDS h).

#define NB        8
#define T_STEPS   4096
#define DRES      1024
#define DIN       64
#define CHUNKS    32      // WGs per batch
#define NTHREADS  256

// ws layout: [pairs: 2*NB*DRES uint64 = 128 KB]
#define PAIR_U64S   (2 * NB * DRES)
#define PAIR_BYTES  (PAIR_U64S * sizeof(unsigned long long))

__launch_bounds__(NTHREADS, 1)
__global__ void esn_kernel(const float* __restrict__ u,      // [NB][T][DIN]
                           const float* __restrict__ w_in,   // [DRES][DIN]
                           const float* __restrict__ w,      // [DRES][DRES]
                           const float* __restrict__ w_bias, // [DRES]
                           float* __restrict__ out,          // [NB][T][DRES]
                           unsigned long long* __restrict__ pairs) // [2][NB][DRES]
{
    const int tid   = threadIdx.x;
    const int b     = blockIdx.x & (NB - 1);   // batch -> XCD affinity heuristic
    const int chunk = blockIdx.x >> 3;         // 0..31 row-chunk
    const int rg    = tid >> 5;                // 0..7 row-group (4 rows each)
    const int mc    = tid & 31;                // 0..31 k-lane
    const int row0  = chunk * 32 + rg * 4;     // first of this thread's 4 rows

    __shared__ float h_lds[2][DRES];           // double-buffered hidden state

    // ---- prologue: weights into registers ----
    float wreg[4][32];                         // wreg[i][j] = W[row0+i][mc+32j]
    #pragma unroll
    for (int i = 0; i < 4; ++i) {
        const float* wr = w + (size_t)(row0 + i) * DRES + mc;
        #pragma unroll
        for (int j = 0; j < 32; ++j)
            wreg[i][j] = wr[32 * j];
    }
    float win0[4], win1[4];                    // w_in[row][2mc], w_in[row][2mc+1]
    #pragma unroll
    for (int i = 0; i < 4; ++i) {
        win0[i] = w_in[(row0 + i) * DIN + 2 * mc];
        win1[i] = w_in[(row0 + i) * DIN + 2 * mc + 1];
    }
    float bias[4];
    #pragma unroll
    for (int i = 0; i < 4; ++i)
        bias[i] = w_bias[row0 + i];

    // h_0 = 0 (iteration t reads h_lds[t&1]; t=0 reads buffer 0)
    #pragma unroll
    for (int k = tid; k < DRES; k += NTHREADS)
        h_lds[0][k] = 0.0f;
    __syncthreads();

    const float* ub = u + (size_t)b * T_STEPS * DIN;
    float2 ucur = *(const float2*)(ub + 2 * mc);   // u_0 slice

    #pragma unroll 1
    for (int t = 0; t < T_STEPS; ++t) {
        // prefetch next step's u slice (hidden behind compute+sync)
        const int tn = (t + 1 < T_STEPS) ? (t + 1) : t;
        const float2 unext = *(const float2*)(ub + (size_t)tn * DIN + 2 * mc);

        // input projection + recurrent matvec (W in regs, h bcast from LDS)
        const float* hl = h_lds[t & 1];
        float acc[4];
        #pragma unroll
        for (int i = 0; i < 4; ++i)
            acc[i] = fmaf(win0[i], ucur.x, win1[i] * ucur.y);
        #pragma unroll
        for (int j = 0; j < 32; ++j) {
            const float hv = hl[mc + 32 * j];
            #pragma unroll
            for (int i = 0; i < 4; ++i)
                acc[i] = fmaf(wreg[i][j], hv, acc[i]);
        }

        // butterfly reduce across the 32 k-lanes (stays within 32-lane halves)
        #pragma unroll
        for (int d = 1; d < 32; d <<= 1) {
            #pragma unroll
            for (int i = 0; i < 4; ++i)
                acc[i] += __shfl_xor(acc[i], d, 64);
        }

        // tanh on all lanes (uniform, no divergence)
        float x[4];
        #pragma unroll
        for (int i = 0; i < 4; ++i) {
            const float z = acc[i] + bias[i];
            const float e = __expf(2.0f * z);
            x[i] = 1.0f - 2.0f / (e + 1.0f);
        }

        // ---- publish FIRST (critical path): (value, tag) pairs, relaxed agent ----
        const unsigned int tag = (unsigned int)(t + 1);
        unsigned long long* pb = pairs + (size_t)(t & 1) * NB * DRES + (size_t)b * DRES;
        if (mc < 4) {
            const float v = (mc & 2) ? ((mc & 1) ? x[3] : x[2])
                                     : ((mc & 1) ? x[1] : x[0]);
            const unsigned long long pk =
                ((unsigned long long)tag << 32) | (unsigned long long)__float_as_uint(v);
            __hip_atomic_store(pb + row0 + mc, pk,
                               __ATOMIC_RELAXED, __HIP_MEMORY_SCOPE_AGENT);
        }

        // output store (off critical path; cached, lazy writeback)
        if (mc == 0) {
            *(float4*)(out + ((size_t)b * T_STEPS + t) * DRES + row0) =
                make_float4(x[0], x[1], x[2], x[3]);
        }
        ucur = unext;

        if (t + 1 == T_STEPS) break;

        // ---- poll 4 pairs (rows tid*4..tid*4+3) until tagged, restage to LDS ----
        const unsigned long long* pp = pb + tid * 4;
        unsigned long long p0, p1, p2, p3;
        for (;;) {
            p0 = __hip_atomic_load(pp + 0, __ATOMIC_RELAXED, __HIP_MEMORY_SCOPE_AGENT);
            p1 = __hip_atomic_load(pp + 1, __ATOMIC_RELAXED, __HIP_MEMORY_SCOPE_AGENT);
            p2 = __hip_atomic_load(pp + 2, __ATOMIC_RELAXED, __HIP_MEMORY_SCOPE_AGENT);
            p3 = __hip_atomic_load(pp + 3, __ATOMIC_RELAXED, __HIP_MEMORY_SCOPE_AGENT);
            if ((unsigned int)(p0 >> 32) == tag && (unsigned int)(p1 >> 32) == tag &&
                (unsigned int)(p2 >> 32) == tag && (unsigned int)(p3 >> 32) == tag)
                break;
            __builtin_amdgcn_s_sleep(1);
        }
        float* hn = h_lds[(t + 1) & 1] + tid * 4;
        hn[0] = __uint_as_float((unsigned int)p0);
        hn[1] = __uint_as_float((unsigned int)p1);
        hn[2] = __uint_as_float((unsigned int)p2);
        hn[3] = __uint_as_float((unsigned int)p3);
        __syncthreads();   // restage -> compute RAW (the only barrier in the loop)
    }
}

extern "C" void kernel_launch(void* const* d_in, const int* in_sizes, int n_in,
                              void* d_out, int out_size, void* d_ws, size_t ws_size,
                              hipStream_t stream) {
    const float* u      = (const float*)d_in[0];
    const float* w_in   = (const float*)d_in[1];
    const float* w      = (const float*)d_in[2];
    const float* w_bias = (const float*)d_in[3];
    float* out = (float*)d_out;

    unsigned long long* pairs = (unsigned long long*)d_ws;

    // clear tags (cheap insurance; poison 0xAAAAAAAA can't equal tags 1..4096,
    // but stale tags from an unpoisoned prior run would be fatal)
    hipMemsetAsync(pairs, 0, PAIR_BYTES, stream);

    esn_kernel<<<NB * CHUNKS, NTHREADS, 0, stream>>>(u, w_in, w, w_bias, out, pairs);
}